// Round 1
// 345.733 us; speedup vs baseline: 1.0046x; 1.0046x over previous
//
#include <hip/hip_runtime.h>

// MaxUnpooling2D: out[b, 2h+dh, 2w+dw, c] = updates[b,h,w,c] where mask encodes
// the per-batch flat index ((2h+dh)*WO + (2w+dw))*C + c; all other positions 0.
//
// R4: OUTPUT-MAJOR GATHER. Previous version was input-owned (1 thread per input
// cell writes its 4 window positions): every store instruction had lane-groups
// at 512B stride writing 256B chunks of 16B nt-stores -> strided streaming
// writes that can't merge into dense bursts. Now 1 thread per OUTPUT float4:
//   out[t] = (mask[cell(t)] == flat(t)) ? upd[cell(t)] : 0
// The output index IS the thread index -> every wave writes 1KiB fully
// contiguous, grid streams linearly (same pattern as the 6.58 TB/s fill
// kernel). Loads are 4x duplicated (wo-parity: in-wave broadcast via the
// coalescer; ho-parity: L2 hit, reusing block is 16 blocks away = same XCD
// under mod-8 round-robin), so loads are CACHED (no nontemporal -- nt loads
// would skip L2 allocation and double read traffic). Stores stay nontemporal:
// output is written once and never re-read.
// Total HBM traffic: 64 MiB upd + 64 MiB mask + 256 MiB out = 384 MiB.

constexpr int B  = 16;
constexpr int H  = 128;
constexpr int W  = 128;
constexpr int C  = 64;
constexpr int UP = 2;
constexpr int HO = H * UP;   // 256
constexpr int WO = W * UP;   // 256
constexpr int C4 = C / 4;    // 16 float4 per channel-row

typedef float f32x4 __attribute__((ext_vector_type(4)));
typedef int   i32x4 __attribute__((ext_vector_type(4)));

__global__ __launch_bounds__(256) void unpool_gather(
    const f32x4* __restrict__ upd,   // [B*H*W*C4]
    const i32x4* __restrict__ msk,   // [B*H*W*C4]
    f32x4*       __restrict__ out)   // [B*HO*WO*C4]
{
    const int t = blockIdx.x * blockDim.x + threadIdx.x;   // [0, B*HO*WO*C4)

    // decode output coords: c4 fastest (4 bits), wo (8 bits), ho (8 bits), b (4 bits)
    const int c4 = t & (C4 - 1);
    const int wo = (t >> 4) & (WO - 1);
    const int ho = (t >> 12) & (HO - 1);
    const int b  = t >> 20;

    // source input cell for this output position
    const int in_idx = ((b * H + (ho >> 1)) * W + (wo >> 1)) * C4 + c4;

    const f32x4 u = upd[in_idx];   // cached: 4x reuse (wo parity in-wave, ho parity via L2)
    const i32x4 m = msk[in_idx];

    // per-batch flat float index of component 0 at this output position
    const int flat0 = (ho * WO + wo) * C + c4 * 4;

    f32x4 v;
    v.x = (m.x == flat0 + 0) ? u.x : 0.0f;
    v.y = (m.y == flat0 + 1) ? u.y : 0.0f;
    v.z = (m.z == flat0 + 2) ? u.z : 0.0f;
    v.w = (m.w == flat0 + 3) ? u.w : 0.0f;

    // out layout [b][ho][wo][c4] matches the t decode exactly -> linear store
    __builtin_nontemporal_store(v, &out[t]);
}

extern "C" void kernel_launch(void* const* d_in, const int* in_sizes, int n_in,
                              void* d_out, int out_size, void* d_ws, size_t ws_size,
                              hipStream_t stream) {
    const f32x4* upd = (const f32x4*)d_in[0];
    const i32x4* msk = (const i32x4*)d_in[1];
    f32x4*       out = (f32x4*)d_out;

    const int n_threads = B * HO * WO * C4;        // 16,777,216
    const int block = 256;
    const int grid  = n_threads / block;           // 65,536

    unpool_gather<<<grid, block, 0, stream>>>(upd, msk, out);
}